// Round 3
// baseline (25.569 us; speedup 1.0000x reference)
//
#include <hip/hip_runtime.h>

#define LN_EPS 1e-5f

// One block per sample n. 256 threads; each thread owns 2 adjacent d columns.
__global__ __launch_bounds__(256) void choquet_fused_kernel(
    const float* __restrict__ x,      // (N, 8, 512)
    const float* __restrict__ FM,     // (255, 8)
    const float* __restrict__ lnw,    // (8, 512)
    const float* __restrict__ lnb,    // (8, 512)
    const float* __restrict__ prelu,  // (1,)
    float* __restrict__ out)          // (N, 8, 512)
{
    constexpr int H = 8;
    // FM rows padded 8 -> 10 dwords (40 B): 8B-aligned rows for b64 reads.
    __shared__ float2 fm_s[255 * 5];
    __shared__ float red[8];          // 4 waves x {sum, sumsq}

    const int n = blockIdx.x;
    const int t = threadIdx.x;

    // ---- issue FM staging loads + x loads first (latency hides under sort) --
    float4 fmv0 = ((const float4*)FM)[t];          // t < 256 < 510 always valid
    float4 fmv1;
    const int i1 = t + 256;
    if (i1 < 510) fmv1 = ((const float4*)FM)[i1];

    const float2* xp = (const float2*)(x + (size_t)n * 4096) + t;
    float2 xv[8];
#pragma unroll
    for (int s = 0; s < 8; ++s) xv[s] = xp[s * 256];

    // ---- stage FM into LDS (row stride 10 floats) ----
    {
        const int r = t >> 1, half = t & 1;
        fm_s[5 * r + 2 * half]     = make_float2(fmv0.x, fmv0.y);
        fm_s[5 * r + 2 * half + 1] = make_float2(fmv0.z, fmv0.w);
        if (i1 < 510) {
            const int r2 = i1 >> 1, h2 = i1 & 1;
            fm_s[5 * r2 + 2 * h2]     = make_float2(fmv1.x, fmv1.y);
            fm_s[5 * r2 + 2 * h2 + 1] = make_float2(fmv1.z, fmv1.w);
        }
    }

    // ---- stable-equivalent descending sort of both columns ----
    // (ties contribute zero weight: equal adjacent sorted values have diff 0
    //  and identical cumulative mask after the group, so value-only compare
    //  is exact.)
    float vv[2][8];
    int   ii[2][8];
#pragma unroll
    for (int s = 0; s < 8; ++s) {
        vv[0][s] = xv[s].x; vv[1][s] = xv[s].y;
        ii[0][s] = s;       ii[1][s] = s;
    }

#define CE(c, a, b)                                                           \
    {                                                                         \
        if (vv[c][a] < vv[c][b]) {                                            \
            float tv = vv[c][a]; vv[c][a] = vv[c][b]; vv[c][b] = tv;          \
            int   ti = ii[c][a]; ii[c][a] = ii[c][b]; ii[c][b] = ti;          \
        }                                                                     \
    }
#pragma unroll
    for (int c = 0; c < 2; ++c) {
        CE(c, 0, 1) CE(c, 2, 3) CE(c, 4, 5) CE(c, 6, 7)
        CE(c, 0, 2) CE(c, 1, 3) CE(c, 4, 6) CE(c, 5, 7)
        CE(c, 1, 2) CE(c, 5, 6) CE(c, 0, 4) CE(c, 3, 7)
        CE(c, 1, 5) CE(c, 2, 6)
        CE(c, 1, 4) CE(c, 3, 6)
        CE(c, 2, 4) CE(c, 3, 5)
        CE(c, 3, 4)
    }
#undef CE

    __syncthreads();   // FM staged

    // ---- Choquet accumulation, both columns interleaved ----
    float y[2][8];
#pragma unroll
    for (int c = 0; c < 2; ++c)
#pragma unroll
        for (int h = 0; h < H; ++h) y[c][h] = 0.f;

    int mask0 = 0, mask1 = 0;
#pragma unroll
    for (int s = 0; s < 8; ++s) {
        mask0 |= 1 << ii[0][s];
        mask1 |= 1 << ii[1][s];
        const float d0 = vv[0][s] - (s < 7 ? vv[0][s + 1] : 0.f);
        const float d1 = vv[1][s] - (s < 7 ? vv[1][s + 1] : 0.f);
        const float2* row0 = &fm_s[5 * (mask0 - 1)];
        const float2* row1 = &fm_s[5 * (mask1 - 1)];
        const float2 a0 = row0[0], a1 = row0[1], a2 = row0[2], a3 = row0[3];
        const float2 b0 = row1[0], b1 = row1[1], b2 = row1[2], b3 = row1[3];
        y[0][0] += d0 * a0.x; y[0][1] += d0 * a0.y;
        y[0][2] += d0 * a1.x; y[0][3] += d0 * a1.y;
        y[0][4] += d0 * a2.x; y[0][5] += d0 * a2.y;
        y[0][6] += d0 * a3.x; y[0][7] += d0 * a3.y;
        y[1][0] += d1 * b0.x; y[1][1] += d1 * b0.y;
        y[1][2] += d1 * b1.x; y[1][3] += d1 * b1.y;
        y[1][4] += d1 * b2.x; y[1][5] += d1 * b2.y;
        y[1][6] += d1 * b3.x; y[1][7] += d1 * b3.y;
    }

    // ---- issue LayerNorm param loads now; latency hides under reduction ----
    float2 w[H], b[H];
#pragma unroll
    for (int h = 0; h < H; ++h) {
        w[h] = ((const float2*)lnw)[h * 256 + t];
        b[h] = ((const float2*)lnb)[h * 256 + t];
    }
    const float pw = prelu[0];

    // ---- block mean/var over 4096 values ----
    float s1 = 0.f, s2 = 0.f;
#pragma unroll
    for (int c = 0; c < 2; ++c)
#pragma unroll
        for (int h = 0; h < H; ++h) { s1 += y[c][h]; s2 += y[c][h] * y[c][h]; }
#pragma unroll
    for (int off = 32; off > 0; off >>= 1) {
        s1 += __shfl_xor(s1, off);
        s2 += __shfl_xor(s2, off);
    }
    const int wid = t >> 6;
    if ((t & 63) == 0) { red[wid * 2] = s1; red[wid * 2 + 1] = s2; }
    __syncthreads();

    float t1 = 0.f, t2 = 0.f;
#pragma unroll
    for (int wv = 0; wv < 4; ++wv) { t1 += red[wv * 2]; t2 += red[wv * 2 + 1]; }
    const float mean = t1 * (1.0f / 4096.0f);
    float var = t2 * (1.0f / 4096.0f) - mean * mean;
    var = var < 0.f ? 0.f : var;
    const float rstd = rsqrtf(var + LN_EPS);

    float2* op = (float2*)(out + (size_t)n * 4096) + t;
#pragma unroll
    for (int h = 0; h < H; ++h) {
        float val0 = (y[0][h] - mean) * rstd * w[h].x + b[h].x;
        float val1 = (y[1][h] - mean) * rstd * w[h].y + b[h].y;
        val0 = val0 > 0.f ? val0 : pw * val0;
        val1 = val1 > 0.f ? val1 : pw * val1;
        op[h * 256] = make_float2(val0, val1);
    }
}

extern "C" void kernel_launch(void* const* d_in, const int* in_sizes, int n_in,
                              void* d_out, int out_size, void* d_ws, size_t ws_size,
                              hipStream_t stream) {
    const float* x     = (const float*)d_in[0];
    const float* FM    = (const float*)d_in[1];
    const float* lnw   = (const float*)d_in[2];
    const float* lnb   = (const float*)d_in[3];
    const float* prelu = (const float*)d_in[4];
    float* out = (float*)d_out;

    const int N = in_sizes[0] / (8 * 512);
    choquet_fused_kernel<<<N, 256, 0, stream>>>(x, FM, lnw, lnb, prelu, out);
}